// Round 15
// baseline (189.235 us; speedup 1.0000x reference)
//
#include <hip/hip_runtime.h>

// B=2, L=4096, D=512, H=8, DK=64. out = Attn(x W_qkv^T) W_o^T, fp32 io.
// R23 = exact R20 revert (best verified: 183.9us). R21/R22 proved the
// x-cast-into-qkv fusion is net-negative in both serial and prefetched
// forms (fp32 A-path doubles staged bytes; castall is already BW-bound).
// Config: castall (full, 5120 blocks) -> qkv_gemm (128x128, bf16 gload_lds)
// -> attn (R17 structure: CBIAS perm-pack, no setprio -- frozen; every
// scheduling construct spills at the (256,4) reg knife-edge) -> out_gemm
// (fused combine, 32x128 tiles, 4 blocks/CU, A-reg prefetch).

#define Bq 2
#define Lq 4096
#define Dq 512
#define Hq 8
#define DKq 64
#define PST 72  // P row stride (elems): 144B -> 2-way bank aliasing only (free)
#define CBIAS 0.0037523f  // log2(1 + 2^-7/3): truncation -> ~round-half-up

using short8  = __attribute__((ext_vector_type(8))) short;
using ushort8 = __attribute__((ext_vector_type(8))) unsigned short;
using float4v = __attribute__((ext_vector_type(4))) float;
using half4   = __attribute__((ext_vector_type(4))) _Float16;
using half8   = __attribute__((ext_vector_type(8))) _Float16;
typedef unsigned short u16;
typedef unsigned int   u32;

__device__ __forceinline__ u16 f2bf(float f) {
    u32 u = __float_as_uint(f);
    u += 0x7fffu + ((u >> 16) & 1u);   // RNE
    return (u16)(u >> 16);
}

__device__ __forceinline__ float exp2fast(float x) {
#if __has_builtin(__builtin_amdgcn_exp2f)
    return __builtin_amdgcn_exp2f(x);
#else
    return exp2f(x);
#endif
}

__device__ __forceinline__ float4v mfma16(short8 a, short8 b, float4v c) {
    return __builtin_amdgcn_mfma_f32_16x16x32_bf16(a, b, c, 0, 0, 0);
}

__device__ __forceinline__ void gload_lds16(const u16* g, u16* l) {
    __builtin_amdgcn_global_load_lds(
        (const __attribute__((address_space(1))) unsigned int*)g,
        (__attribute__((address_space(3))) unsigned int*)l,
        16, 0, 0);
}

// ---------------- fused cast fp32 -> bf16 ----------------
__global__ __launch_bounds__(256) void castall(const float* __restrict__ x,
                                               const float* __restrict__ wq,
                                               const float* __restrict__ wo,
                                               u16* __restrict__ xb,
                                               u16* __restrict__ wqb,
                                               u16* __restrict__ wob) {
    int g = blockIdx.x;
    const float* s; u16* d; int base;
    if (g < 4096)      { s = x;  d = xb;  base = g * 1024; }
    else if (g < 4864) { s = wq; d = wqb; base = (g - 4096) * 1024; }
    else               { s = wo; d = wob; base = (g - 4864) * 1024; }
    int i = base + threadIdx.x * 4;
    float4 f = *(const float4*)&s[i];
    ushort4 o;
    o.x = f2bf(f.x); o.y = f2bf(f.y); o.z = f2bf(f.z); o.w = f2bf(f.w);
    *(ushort4*)&d[i] = o;
}

// ---------------- QKV proj: 128x128 tile; LDS-bounced coalesced epilogue -----
// q prescaled by 0.125*log2(e) (softmax done in exp2 domain); k,v plain.
__global__ __launch_bounds__(256) void qkv_gemm(const u16* __restrict__ A,
                                                const u16* __restrict__ Bw,
                                                u16* __restrict__ qb,
                                                u16* __restrict__ kb,
                                                u16* __restrict__ vt) {
    __shared__ __align__(16) union {
        struct { u16 A[128 * 64]; u16 B[128 * 64]; } s;
        u16 epi[128 * 134];
    } sm;
    const int m0 = blockIdx.x * 128, n0 = blockIdx.y * 128;
    const int tid = threadIdx.x, w = tid >> 6, lane = tid & 63;
    const int l15 = lane & 15, quad = lane >> 4;
    const int wy = w & 1, wx = w >> 1;
    const int r8 = lane >> 3, c8 = lane & 7, csw = c8 ^ r8;
    const int sw = l15 & 7;

    float4v acc[4][4];
    float4v zero = {0.f, 0.f, 0.f, 0.f};
#pragma unroll
    for (int mi = 0; mi < 4; mi++)
#pragma unroll
        for (int ni = 0; ni < 4; ni++) acc[mi][ni] = zero;

    for (int k0 = 0; k0 < 512; k0 += 64) {
#pragma unroll
        for (int i = 0; i < 4; i++) {
            int row = w * 32 + i * 8;
            gload_lds16(&A[(size_t)(m0 + row + r8) * 512 + k0 + csw * 8], &sm.s.A[row * 64]);
            gload_lds16(&Bw[(size_t)(n0 + row + r8) * 512 + k0 + csw * 8], &sm.s.B[row * 64]);
        }
        __syncthreads();
        short8 af0[4], af1[4], bf0[4], bf1[4];
#pragma unroll
        for (int t = 0; t < 4; t++) {
            int rowA = wy * 64 + t * 16 + l15;
            af0[t] = *(const short8*)&sm.s.A[rowA * 64 + ((quad ^ sw) * 8)];
            af1[t] = *(const short8*)&sm.s.A[rowA * 64 + (((quad + 4) ^ sw) * 8)];
            int rowB = wx * 64 + t * 16 + l15;
            bf0[t] = *(const short8*)&sm.s.B[rowB * 64 + ((quad ^ sw) * 8)];
            bf1[t] = *(const short8*)&sm.s.B[rowB * 64 + (((quad + 4) ^ sw) * 8)];
        }
#pragma unroll
        for (int mi = 0; mi < 4; mi++)
#pragma unroll
            for (int ni = 0; ni < 4; ni++) {
                acc[mi][ni] = mfma16(af0[mi], bf0[ni], acc[mi][ni]);
                acc[mi][ni] = mfma16(af1[mi], bf1[ni], acc[mi][ni]);
            }
        __syncthreads();
    }

    const int sel = n0 >> 9;   // block-uniform: 0=q,1=k,2=v
    if (sel < 2) {
        const float sc = (sel == 0) ? 0.18033688f : 1.0f;  // 0.125*log2(e)
#pragma unroll
        for (int mi = 0; mi < 4; mi++)
#pragma unroll
            for (int ni = 0; ni < 4; ni++)
#pragma unroll
                for (int r = 0; r < 4; r++)
                    sm.epi[(wy * 64 + mi * 16 + quad * 4 + r) * 134 + wx * 64 + ni * 16 + l15] =
                        f2bf(acc[mi][ni][r] * sc);
        __syncthreads();
        u16* tgt = (sel == 0) ? qb : kb;
#pragma unroll
        for (int i = 0; i < 8; i++) {
            int flat = i * 2048 + tid * 8;
            int row = flat >> 7, col = flat & 127;
            ushort8 vv = *(const ushort8*)&sm.epi[row * 134 + col];
            int dg = (n0 & 511) + col, h = dg >> 6, dk = dg & 63;
            int mm = m0 + row, b = mm >> 12, l = mm & 4095;
            *(ushort8*)&tgt[((size_t)(b * Hq + h) * Lq + l) * DKq + dk] = vv;
        }
    } else {
#pragma unroll
        for (int mi = 0; mi < 4; mi++)
#pragma unroll
            for (int ni = 0; ni < 4; ni++) {
                ushort4 v4;
                v4.x = f2bf(acc[mi][ni][0]); v4.y = f2bf(acc[mi][ni][1]);
                v4.z = f2bf(acc[mi][ni][2]); v4.w = f2bf(acc[mi][ni][3]);
                *(ushort4*)&sm.epi[(wx * 64 + ni * 16 + l15) * 134 + wy * 64 + mi * 16 + quad * 4] = v4;
            }
        __syncthreads();
#pragma unroll
        for (int i = 0; i < 8; i++) {
            int flat = i * 2048 + tid * 8;
            int vrow = flat >> 7, vcol = flat & 127;
            ushort8 vv = *(const ushort8*)&sm.epi[vrow * 134 + vcol];
            int dg = (n0 & 511) + vrow, h = dg >> 6, dk = dg & 63;
            int mm = m0 + vcol, b = mm >> 12, l = mm & 4095;
            *(ushort8*)&vt[((size_t)(b * Hq + h) * DKq + dk) * Lq + l] = vv;
        }
    }
}

// ---------------- attention: exact R17 (87.5us proven; no setprio!) ---------
__global__ __launch_bounds__(256, 4) void attn_kern(const u16* __restrict__ qb,
                                                    const u16* __restrict__ kb,
                                                    const u16* __restrict__ vt,
                                                    _Float16* __restrict__ op0,
                                                    _Float16* __restrict__ op1,
                                                    float* __restrict__ denp) {
    __shared__ __align__(16) u16 Ks[64 * 64];
    __shared__ __align__(16) u16 Vs[64 * 64];
    __shared__ __align__(16) u16 Ps[4 * 32 * PST];
    const int g = blockIdx.x;          // 1024
    const int xcd = g & 7, idx = g >> 3;
    const int bh = xcd * 2 + (idx & 1);
    const int rest = idx >> 1;
    const int split = rest & 1;
    const int q0 = (rest >> 1) * 128;
    const int tid = threadIdx.x;
    const int w = tid >> 6, lane = tid & 63, l15 = lane & 15, quad = lane >> 4;
    const int r8 = lane >> 3, c8 = lane & 7, csw = c8 ^ r8;
    const int sw = l15 & 7;

    const u16* qbase = qb + (size_t)bh * Lq * DKq;
    const u16* kbase = kb + (size_t)bh * Lq * DKq;
    const u16* vbase = vt + (size_t)bh * DKq * Lq;

    short8 aq0[2], aq1[2];
#pragma unroll
    for (int s = 0; s < 2; s++) {
        int qrow = q0 + w * 32 + s * 16 + l15;
        aq0[s] = *(const short8*)&qbase[(size_t)qrow * DKq + quad * 8];
        aq1[s] = *(const short8*)&qbase[(size_t)qrow * DKq + 32 + quad * 8];
    }

    short8 ones8;
#pragma unroll
    for (int j = 0; j < 8; j++) ones8[j] = (short)0x3F80;  // bf16 1.0

    float4v zero = {0.f, 0.f, 0.f, 0.f};
    // exp2-domain bias: truncating pack of exp2(S + CBIAS) ~= RHU(exp2(S)).
    const float4v cinit = {CBIAS, CBIAS, CBIAS, CBIAS};
    float4v oacc[2][4], den[2];
#pragma unroll
    for (int s = 0; s < 2; s++) {
        den[s] = zero;
#pragma unroll
        for (int n = 0; n < 4; n++) oacc[s][n] = zero;
    }

    u16* Pw = Ps + w * 32 * PST;
    const int j0base = split * 2048;

    for (int jt = 0; jt < 32; jt++) {
        int j0 = j0base + jt * 64;
        if (w < 2) {
#pragma unroll
            for (int i = 0; i < 4; i++) {
                int base = w * 32 + i * 8;
                gload_lds16(&kbase[(size_t)(j0 + base + r8) * DKq + csw * 8], &Ks[base * 64]);
            }
        } else {
#pragma unroll
            for (int i = 0; i < 4; i++) {
                int base = (w - 2) * 32 + i * 8;
                gload_lds16(&vbase[(size_t)(base + r8) * Lq + j0 + csw * 8], &Vs[base * 64]);
            }
        }
        __syncthreads();

        short8 kf0[4], kf1[4], vf0[4], vf1[4];
#pragma unroll
        for (int n = 0; n < 4; n++) {
            int row = n * 16 + l15;
            kf0[n] = *(const short8*)&Ks[row * 64 + ((quad ^ sw) * 8)];
            kf1[n] = *(const short8*)&Ks[row * 64 + (((quad + 4) ^ sw) * 8)];
            vf0[n] = *(const short8*)&Vs[row * 64 + ((quad ^ sw) * 8)];
            vf1[n] = *(const short8*)&Vs[row * 64 + (((quad + 4) ^ sw) * 8)];
        }

        // S^T = K Q^T (acc init = CBIAS) -> P = exp2 -> perm pack (truncate)
#pragma unroll
        for (int s = 0; s < 2; s++) {
#pragma unroll
            for (int nk = 0; nk < 4; nk++) {
                float4v sv = cinit;
                sv = mfma16(kf0[nk], aq0[s], sv);
                sv = mfma16(kf1[nk], aq1[s], sv);
                u32 u0 = __float_as_uint(exp2fast(sv[0]));
                u32 u1 = __float_as_uint(exp2fast(sv[1]));
                u32 u2 = __float_as_uint(exp2fast(sv[2]));
                u32 u3 = __float_as_uint(exp2fast(sv[3]));
                uint2 pv;
                pv.x = __builtin_amdgcn_perm(u1, u0, 0x07060302u);
                pv.y = __builtin_amdgcn_perm(u3, u2, 0x07060302u);
                *(uint2*)&Pw[(s * 16 + l15) * PST + nk * 16 + quad * 4] = pv;
            }
        }

        // O += P V ; den += P . 1
#pragma unroll
        for (int s = 0; s < 2; s++) {
            short8 ap0 = *(const short8*)&Pw[(s * 16 + l15) * PST + quad * 8];
            short8 ap1 = *(const short8*)&Pw[(s * 16 + l15) * PST + 32 + quad * 8];
            den[s] = mfma16(ap0, ones8, den[s]);
            den[s] = mfma16(ap1, ones8, den[s]);
#pragma unroll
            for (int n = 0; n < 4; n++) {
                oacc[s][n] = mfma16(ap0, vf0[n], oacc[s][n]);
                oacc[s][n] = mfma16(ap1, vf1[n], oacc[s][n]);
            }
        }
        __syncthreads();
    }

    // epilogue: write normalized partial O (fp16) + partial den (fp32)
    _Float16* op = split ? op1 : op0;
#pragma unroll
    for (int s = 0; s < 2; s++)
#pragma unroll
        for (int r = 0; r < 4; r++) {
            float dv = den[s][r];
            float rd = __builtin_amdgcn_rcpf(dv);
            int row = q0 + w * 32 + s * 16 + quad * 4 + r;
            if (l15 == 0) denp[(size_t)(split * 16 + bh) * Lq + row] = dv;
#pragma unroll
            for (int n = 0; n < 4; n++)
                op[((size_t)bh * Lq + row) * DKq + n * 16 + l15] =
                    (_Float16)(oacc[s][n][r] * rd);
        }
}

// ---------------- output projection, fused combine, 32x128 tiles (R20) ------
// ctx = (o0*d0 + o1*d1)/(d0+d1) in A-staging (K-slice k0 <-> head h=k0>>6).
// Grid (256,4) = 1024 blocks = 4 blocks/CU. A-reg prefetch: combine consumes
// regs loaded a full iteration ago.
__global__ __launch_bounds__(256) void out_gemm(const _Float16* __restrict__ op0,
                                                const _Float16* __restrict__ op1,
                                                const float* __restrict__ denp,
                                                const u16* __restrict__ Bw,
                                                float* __restrict__ out) {
    __shared__ __align__(16) union {
        struct { u16 A[32 * 64]; u16 B[128 * 64]; } s;
        float fepi[32 * 132];
    } sm;
    const int m0 = blockIdx.x * 32, n0 = blockIdx.y * 128;
    const int tid = threadIdx.x, w = tid >> 6, lane = tid & 63;
    const int l15 = lane & 15, quad = lane >> 4;
    const int r8 = lane >> 3, c8 = lane & 7, csw = c8 ^ r8;
    const int sw = l15 & 7;
    const int arow = tid >> 3;           // 0..31: one A row-segment per thread

    float4v acc[2][2];
    float4v zero = {0.f, 0.f, 0.f, 0.f};
#pragma unroll
    for (int mi = 0; mi < 2; mi++)
#pragma unroll
        for (int ni = 0; ni < 2; ni++) acc[mi][ni] = zero;

    // per-thread invariant A addresses: addr(h) = abase + h*Lq*DKq (elems)
    const int m = m0 + arow;
    const int b = m >> 12, l = m & 4095;
    const size_t abase = ((size_t)b * Hq * Lq + l) * DKq + csw * 8;
    const size_t dbase = (size_t)b * Hq * Lq + l;

    // prologue: prefetch A-regs for h=0
    half8 ph0 = *(const half8*)&op0[abase];
    half8 ph1 = *(const half8*)&op1[abase];
    float pd0 = denp[dbase];
    float pd1 = denp[dbase + (size_t)16 * Lq];

    for (int k0 = 0; k0 < 512; k0 += 64) {
        const int h = k0 >> 6;
        // ---- B staging: async gload_lds (128 rows) ----
#pragma unroll
        for (int i = 0; i < 4; i++) {
            int row = w * 32 + i * 8;
            gload_lds16(&Bw[(size_t)(n0 + row + r8) * 512 + k0 + csw * 8], &sm.s.B[row * 64]);
        }
        // ---- A write: combine from regs prefetched LAST iteration ----
        {
            float rs = __builtin_amdgcn_rcpf(pd0 + pd1);
            float a = pd0 * rs, c = pd1 * rs;
            ushort8 o;
#pragma unroll
            for (int e = 0; e < 8; e++)
                o[e] = f2bf((float)ph0[e] * a + (float)ph1[e] * c);
            *(ushort8*)&sm.s.A[arow * 64 + c8 * 8] = o;
        }
        __syncthreads();
        // ---- prefetch A-regs for h+1 (hidden under frag reads + MFMA) ----
        if (h + 1 < 8) {
            size_t ab = abase + (size_t)(h + 1) * Lq * DKq;
            size_t db = dbase + (size_t)(h + 1) * Lq;
            ph0 = *(const half8*)&op0[ab];
            ph1 = *(const half8*)&op1[ab];
            pd0 = denp[db];
            pd1 = denp[db + (size_t)16 * Lq];
        }
        short8 af0[2], af1[2], bf0[2], bf1[2];
#pragma unroll
        for (int t = 0; t < 2; t++) {
            int rowA = t * 16 + l15;
            af0[t] = *(const short8*)&sm.s.A[rowA * 64 + ((quad ^ sw) * 8)];
            af1[t] = *(const short8*)&sm.s.A[rowA * 64 + (((quad + 4) ^ sw) * 8)];
        }
#pragma unroll
        for (int n = 0; n < 2; n++) {
            int rowB = w * 32 + n * 16 + l15;
            bf0[n] = *(const short8*)&sm.s.B[rowB * 64 + ((quad ^ sw) * 8)];
            bf1[n] = *(const short8*)&sm.s.B[rowB * 64 + (((quad + 4) ^ sw) * 8)];
        }
#pragma unroll
        for (int mi = 0; mi < 2; mi++)
#pragma unroll
            for (int ni = 0; ni < 2; ni++) {
                acc[mi][ni] = mfma16(af0[mi], bf0[ni], acc[mi][ni]);
                acc[mi][ni] = mfma16(af1[mi], bf1[ni], acc[mi][ni]);
            }
        __syncthreads();
    }

    // epilogue: 32x128 fp32 tile via LDS bounce, coalesced float4 stores
#pragma unroll
    for (int mi = 0; mi < 2; mi++)
#pragma unroll
        for (int ni = 0; ni < 2; ni++)
#pragma unroll
            for (int r = 0; r < 4; r++)
                sm.fepi[(mi * 16 + quad * 4 + r) * 132 + w * 32 + ni * 16 + l15] =
                    acc[mi][ni][r];
    __syncthreads();
#pragma unroll
    for (int i = 0; i < 4; i++) {
        int flat = i * 1024 + tid * 4;
        int lrow = flat >> 7, col = flat & 127;
        float4 vv = *(const float4*)&sm.fepi[lrow * 132 + col];
        *(float4*)&out[(size_t)(m0 + lrow) * 512 + n0 + col] = vv;
    }
}

extern "C" void kernel_launch(void* const* d_in, const int* in_sizes, int n_in,
                              void* d_out, int out_size, void* d_ws, size_t ws_size,
                              hipStream_t stream) {
    const float* x     = (const float*)d_in[0];   // [2,4096,512]
    const float* w_qkv = (const float*)d_in[1];   // [1536,512]
    const float* w_o   = (const float*)d_in[2];   // [512,512]
    float* out = (float*)d_out;

    const size_t N_X   = (size_t)Bq * Lq * Dq;        // 4194304
    const size_t N_WQ  = (size_t)3 * Dq * Dq;         // 786432
    const size_t N_WO  = (size_t)Dq * Dq;             // 262144
    const size_t N_QKV = (size_t)Bq * Hq * Lq * DKq;  // 4194304 each

    u16* xb  = (u16*)d_ws;       // castall in; dead after qkv -> op0
    u16* wqb = xb + N_X;         // dead after qkv -> denp
    u16* wob = wqb + N_WQ;
    u16* qb  = wob + N_WO;
    u16* kb  = qb + N_QKV;
    u16* vt  = kb + N_QKV;
    u16* o1r = vt + N_QKV;       // op1 region

    _Float16* op0  = (_Float16*)xb;
    _Float16* op1  = (_Float16*)o1r;
    float*    denp = (float*)wqb;

    castall<<<dim3(5120), 256, 0, stream>>>(x, w_qkv, w_o, xb, wqb, wob);
    qkv_gemm<<<dim3(64, 12), 256, 0, stream>>>(xb, wqb, qb, kb, vt);
    attn_kern<<<dim3(1024), 256, 0, stream>>>(qb, kb, vt, op0, op1, denp);
    out_gemm<<<dim3(256, 4), 256, 0, stream>>>(op0, op1, denp, wob, out);
}

// Round 16
// 179.102 us; speedup vs baseline: 1.0566x; 1.0566x over previous
//
#include <hip/hip_runtime.h>

// B=2, L=4096, D=512, H=8, DK=64. out = Attn(x W_qkv^T) W_o^T, fp32 io.
// R24 = R20/R23 + the R12-style pipeline reorder applied to QKV_GEMM only:
//   read frags(tile k) -> sync#1 -> stage(tile k+1, same LDS buffer)
//   -> 32 MFMAs -> sync#2 (vmcnt drain now has the whole compute phase of
//   slack instead of zero).
// Why safe HERE and not in attn: attn's (256,4) launch bound left 0 reg
// slack (R9/R13/R18 spilled); qkv has NO launch-bounds cap and the reorder
// extends no live range (all 16 frags already span the MFMA block; only the
// barrier moves). ~160 regs -> 12 waves/CU = grid's own 3-block/CU cap.
// R23 calibrated noise: identical-source spread 183.9-189.2 (+-3us).
// attn frozen at R17; out_gemm = R20; castall unchanged.

#define Bq 2
#define Lq 4096
#define Dq 512
#define Hq 8
#define DKq 64
#define PST 72  // P row stride (elems): 144B -> 2-way bank aliasing only (free)
#define CBIAS 0.0037523f  // log2(1 + 2^-7/3): truncation -> ~round-half-up

using short8  = __attribute__((ext_vector_type(8))) short;
using ushort8 = __attribute__((ext_vector_type(8))) unsigned short;
using float4v = __attribute__((ext_vector_type(4))) float;
using half4   = __attribute__((ext_vector_type(4))) _Float16;
using half8   = __attribute__((ext_vector_type(8))) _Float16;
typedef unsigned short u16;
typedef unsigned int   u32;

__device__ __forceinline__ u16 f2bf(float f) {
    u32 u = __float_as_uint(f);
    u += 0x7fffu + ((u >> 16) & 1u);   // RNE
    return (u16)(u >> 16);
}

__device__ __forceinline__ float exp2fast(float x) {
#if __has_builtin(__builtin_amdgcn_exp2f)
    return __builtin_amdgcn_exp2f(x);
#else
    return exp2f(x);
#endif
}

__device__ __forceinline__ float4v mfma16(short8 a, short8 b, float4v c) {
    return __builtin_amdgcn_mfma_f32_16x16x32_bf16(a, b, c, 0, 0, 0);
}

__device__ __forceinline__ void gload_lds16(const u16* g, u16* l) {
    __builtin_amdgcn_global_load_lds(
        (const __attribute__((address_space(1))) unsigned int*)g,
        (__attribute__((address_space(3))) unsigned int*)l,
        16, 0, 0);
}

// ---------------- fused cast fp32 -> bf16 ----------------
__global__ __launch_bounds__(256) void castall(const float* __restrict__ x,
                                               const float* __restrict__ wq,
                                               const float* __restrict__ wo,
                                               u16* __restrict__ xb,
                                               u16* __restrict__ wqb,
                                               u16* __restrict__ wob) {
    int g = blockIdx.x;
    const float* s; u16* d; int base;
    if (g < 4096)      { s = x;  d = xb;  base = g * 1024; }
    else if (g < 4864) { s = wq; d = wqb; base = (g - 4096) * 1024; }
    else               { s = wo; d = wob; base = (g - 4864) * 1024; }
    int i = base + threadIdx.x * 4;
    float4 f = *(const float4*)&s[i];
    ushort4 o;
    o.x = f2bf(f.x); o.y = f2bf(f.y); o.z = f2bf(f.z); o.w = f2bf(f.w);
    *(ushort4*)&d[i] = o;
}

// ---------------- QKV proj: 128x128 tile; reordered staging (R24) -----------
// q prescaled by 0.125*log2(e) (softmax done in exp2 domain); k,v plain.
__global__ __launch_bounds__(256) void qkv_gemm(const u16* __restrict__ A,
                                                const u16* __restrict__ Bw,
                                                u16* __restrict__ qb,
                                                u16* __restrict__ kb,
                                                u16* __restrict__ vt) {
    __shared__ __align__(16) union {
        struct { u16 A[128 * 64]; u16 B[128 * 64]; } s;
        u16 epi[128 * 134];
    } sm;
    const int m0 = blockIdx.x * 128, n0 = blockIdx.y * 128;
    const int tid = threadIdx.x, w = tid >> 6, lane = tid & 63;
    const int l15 = lane & 15, quad = lane >> 4;
    const int wy = w & 1, wx = w >> 1;
    const int r8 = lane >> 3, c8 = lane & 7, csw = c8 ^ r8;
    const int sw = l15 & 7;

    float4v acc[4][4];
    float4v zero = {0.f, 0.f, 0.f, 0.f};
#pragma unroll
    for (int mi = 0; mi < 4; mi++)
#pragma unroll
        for (int ni = 0; ni < 4; ni++) acc[mi][ni] = zero;

    // stage one 128x64 A-tile + 128x64 B-tile at K offset k0 (async, 0 VGPR)
    auto stage = [&](int k0) {
#pragma unroll
        for (int i = 0; i < 4; i++) {
            int row = w * 32 + i * 8;
            gload_lds16(&A[(size_t)(m0 + row + r8) * 512 + k0 + csw * 8], &sm.s.A[row * 64]);
            gload_lds16(&Bw[(size_t)(n0 + row + r8) * 512 + k0 + csw * 8], &sm.s.B[row * 64]);
        }
    };

    // prologue: stage tile 0; this barrier pays the full drain once.
    stage(0);
    __syncthreads();

    for (int k0 = 0; k0 < 512; k0 += 64) {
        // read fragments of tile k0 into registers
        short8 af0[4], af1[4], bf0[4], bf1[4];
#pragma unroll
        for (int t = 0; t < 4; t++) {
            int rowA = wy * 64 + t * 16 + l15;
            af0[t] = *(const short8*)&sm.s.A[rowA * 64 + ((quad ^ sw) * 8)];
            af1[t] = *(const short8*)&sm.s.A[rowA * 64 + (((quad + 4) ^ sw) * 8)];
            int rowB = wx * 64 + t * 16 + l15;
            bf0[t] = *(const short8*)&sm.s.B[rowB * 64 + ((quad ^ sw) * 8)];
            bf1[t] = *(const short8*)&sm.s.B[rowB * 64 + (((quad + 4) ^ sw) * 8)];
        }
        // sync#1: all waves hold tile k0 in regs; vmcnt already 0 here.
        __syncthreads();
        // overwrite LDS with tile k0+64; compute below touches only regs.
        if (k0 + 64 < 512) stage(k0 + 64);
#pragma unroll
        for (int mi = 0; mi < 4; mi++)
#pragma unroll
            for (int ni = 0; ni < 4; ni++) {
                acc[mi][ni] = mfma16(af0[mi], bf0[ni], acc[mi][ni]);
                acc[mi][ni] = mfma16(af1[mi], bf1[ni], acc[mi][ni]);
            }
        // sync#2: publishes tile k0+64; its vmcnt drain now has the whole
        // MFMA phase (~12 waves x 32 MFMA per CU) of slack.
        __syncthreads();
    }

    const int sel = n0 >> 9;   // block-uniform: 0=q,1=k,2=v
    if (sel < 2) {
        const float sc = (sel == 0) ? 0.18033688f : 1.0f;  // 0.125*log2(e)
#pragma unroll
        for (int mi = 0; mi < 4; mi++)
#pragma unroll
            for (int ni = 0; ni < 4; ni++)
#pragma unroll
                for (int r = 0; r < 4; r++)
                    sm.epi[(wy * 64 + mi * 16 + quad * 4 + r) * 134 + wx * 64 + ni * 16 + l15] =
                        f2bf(acc[mi][ni][r] * sc);
        __syncthreads();
        u16* tgt = (sel == 0) ? qb : kb;
#pragma unroll
        for (int i = 0; i < 8; i++) {
            int flat = i * 2048 + tid * 8;
            int row = flat >> 7, col = flat & 127;
            ushort8 vv = *(const ushort8*)&sm.epi[row * 134 + col];
            int dg = (n0 & 511) + col, h = dg >> 6, dk = dg & 63;
            int mm = m0 + row, b = mm >> 12, l = mm & 4095;
            *(ushort8*)&tgt[((size_t)(b * Hq + h) * Lq + l) * DKq + dk] = vv;
        }
    } else {
#pragma unroll
        for (int mi = 0; mi < 4; mi++)
#pragma unroll
            for (int ni = 0; ni < 4; ni++) {
                ushort4 v4;
                v4.x = f2bf(acc[mi][ni][0]); v4.y = f2bf(acc[mi][ni][1]);
                v4.z = f2bf(acc[mi][ni][2]); v4.w = f2bf(acc[mi][ni][3]);
                *(ushort4*)&sm.epi[(wx * 64 + ni * 16 + l15) * 134 + wy * 64 + mi * 16 + quad * 4] = v4;
            }
        __syncthreads();
#pragma unroll
        for (int i = 0; i < 8; i++) {
            int flat = i * 2048 + tid * 8;
            int vrow = flat >> 7, vcol = flat & 127;
            ushort8 vv = *(const ushort8*)&sm.epi[vrow * 134 + vcol];
            int dg = (n0 & 511) + vrow, h = dg >> 6, dk = dg & 63;
            int mm = m0 + vcol, b = mm >> 12, l = mm & 4095;
            *(ushort8*)&vt[((size_t)(b * Hq + h) * DKq + dk) * Lq + l] = vv;
        }
    }
}

// ---------------- attention: exact R17 (87.5us proven; no setprio!) ---------
__global__ __launch_bounds__(256, 4) void attn_kern(const u16* __restrict__ qb,
                                                    const u16* __restrict__ kb,
                                                    const u16* __restrict__ vt,
                                                    _Float16* __restrict__ op0,
                                                    _Float16* __restrict__ op1,
                                                    float* __restrict__ denp) {
    __shared__ __align__(16) u16 Ks[64 * 64];
    __shared__ __align__(16) u16 Vs[64 * 64];
    __shared__ __align__(16) u16 Ps[4 * 32 * PST];
    const int g = blockIdx.x;          // 1024
    const int xcd = g & 7, idx = g >> 3;
    const int bh = xcd * 2 + (idx & 1);
    const int rest = idx >> 1;
    const int split = rest & 1;
    const int q0 = (rest >> 1) * 128;
    const int tid = threadIdx.x;
    const int w = tid >> 6, lane = tid & 63, l15 = lane & 15, quad = lane >> 4;
    const int r8 = lane >> 3, c8 = lane & 7, csw = c8 ^ r8;
    const int sw = l15 & 7;

    const u16* qbase = qb + (size_t)bh * Lq * DKq;
    const u16* kbase = kb + (size_t)bh * Lq * DKq;
    const u16* vbase = vt + (size_t)bh * DKq * Lq;

    short8 aq0[2], aq1[2];
#pragma unroll
    for (int s = 0; s < 2; s++) {
        int qrow = q0 + w * 32 + s * 16 + l15;
        aq0[s] = *(const short8*)&qbase[(size_t)qrow * DKq + quad * 8];
        aq1[s] = *(const short8*)&qbase[(size_t)qrow * DKq + 32 + quad * 8];
    }

    short8 ones8;
#pragma unroll
    for (int j = 0; j < 8; j++) ones8[j] = (short)0x3F80;  // bf16 1.0

    float4v zero = {0.f, 0.f, 0.f, 0.f};
    // exp2-domain bias: truncating pack of exp2(S + CBIAS) ~= RHU(exp2(S)).
    const float4v cinit = {CBIAS, CBIAS, CBIAS, CBIAS};
    float4v oacc[2][4], den[2];
#pragma unroll
    for (int s = 0; s < 2; s++) {
        den[s] = zero;
#pragma unroll
        for (int n = 0; n < 4; n++) oacc[s][n] = zero;
    }

    u16* Pw = Ps + w * 32 * PST;
    const int j0base = split * 2048;

    for (int jt = 0; jt < 32; jt++) {
        int j0 = j0base + jt * 64;
        if (w < 2) {
#pragma unroll
            for (int i = 0; i < 4; i++) {
                int base = w * 32 + i * 8;
                gload_lds16(&kbase[(size_t)(j0 + base + r8) * DKq + csw * 8], &Ks[base * 64]);
            }
        } else {
#pragma unroll
            for (int i = 0; i < 4; i++) {
                int base = (w - 2) * 32 + i * 8;
                gload_lds16(&vbase[(size_t)(base + r8) * Lq + j0 + csw * 8], &Vs[base * 64]);
            }
        }
        __syncthreads();

        short8 kf0[4], kf1[4], vf0[4], vf1[4];
#pragma unroll
        for (int n = 0; n < 4; n++) {
            int row = n * 16 + l15;
            kf0[n] = *(const short8*)&Ks[row * 64 + ((quad ^ sw) * 8)];
            kf1[n] = *(const short8*)&Ks[row * 64 + (((quad + 4) ^ sw) * 8)];
            vf0[n] = *(const short8*)&Vs[row * 64 + ((quad ^ sw) * 8)];
            vf1[n] = *(const short8*)&Vs[row * 64 + (((quad + 4) ^ sw) * 8)];
        }

        // S^T = K Q^T (acc init = CBIAS) -> P = exp2 -> perm pack (truncate)
#pragma unroll
        for (int s = 0; s < 2; s++) {
#pragma unroll
            for (int nk = 0; nk < 4; nk++) {
                float4v sv = cinit;
                sv = mfma16(kf0[nk], aq0[s], sv);
                sv = mfma16(kf1[nk], aq1[s], sv);
                u32 u0 = __float_as_uint(exp2fast(sv[0]));
                u32 u1 = __float_as_uint(exp2fast(sv[1]));
                u32 u2 = __float_as_uint(exp2fast(sv[2]));
                u32 u3 = __float_as_uint(exp2fast(sv[3]));
                uint2 pv;
                pv.x = __builtin_amdgcn_perm(u1, u0, 0x07060302u);
                pv.y = __builtin_amdgcn_perm(u3, u2, 0x07060302u);
                *(uint2*)&Pw[(s * 16 + l15) * PST + nk * 16 + quad * 4] = pv;
            }
        }

        // O += P V ; den += P . 1
#pragma unroll
        for (int s = 0; s < 2; s++) {
            short8 ap0 = *(const short8*)&Pw[(s * 16 + l15) * PST + quad * 8];
            short8 ap1 = *(const short8*)&Pw[(s * 16 + l15) * PST + 32 + quad * 8];
            den[s] = mfma16(ap0, ones8, den[s]);
            den[s] = mfma16(ap1, ones8, den[s]);
#pragma unroll
            for (int n = 0; n < 4; n++) {
                oacc[s][n] = mfma16(ap0, vf0[n], oacc[s][n]);
                oacc[s][n] = mfma16(ap1, vf1[n], oacc[s][n]);
            }
        }
        __syncthreads();
    }

    // epilogue: write normalized partial O (fp16) + partial den (fp32)
    _Float16* op = split ? op1 : op0;
#pragma unroll
    for (int s = 0; s < 2; s++)
#pragma unroll
        for (int r = 0; r < 4; r++) {
            float dv = den[s][r];
            float rd = __builtin_amdgcn_rcpf(dv);
            int row = q0 + w * 32 + s * 16 + quad * 4 + r;
            if (l15 == 0) denp[(size_t)(split * 16 + bh) * Lq + row] = dv;
#pragma unroll
            for (int n = 0; n < 4; n++)
                op[((size_t)bh * Lq + row) * DKq + n * 16 + l15] =
                    (_Float16)(oacc[s][n][r] * rd);
        }
}

// ---------------- output projection, fused combine, 32x128 tiles (R20) ------
__global__ __launch_bounds__(256) void out_gemm(const _Float16* __restrict__ op0,
                                                const _Float16* __restrict__ op1,
                                                const float* __restrict__ denp,
                                                const u16* __restrict__ Bw,
                                                float* __restrict__ out) {
    __shared__ __align__(16) union {
        struct { u16 A[32 * 64]; u16 B[128 * 64]; } s;
        float fepi[32 * 132];
    } sm;
    const int m0 = blockIdx.x * 32, n0 = blockIdx.y * 128;
    const int tid = threadIdx.x, w = tid >> 6, lane = tid & 63;
    const int l15 = lane & 15, quad = lane >> 4;
    const int r8 = lane >> 3, c8 = lane & 7, csw = c8 ^ r8;
    const int sw = l15 & 7;
    const int arow = tid >> 3;           // 0..31: one A row-segment per thread

    float4v acc[2][2];
    float4v zero = {0.f, 0.f, 0.f, 0.f};
#pragma unroll
    for (int mi = 0; mi < 2; mi++)
#pragma unroll
        for (int ni = 0; ni < 2; ni++) acc[mi][ni] = zero;

    // per-thread invariant A addresses: addr(h) = abase + h*Lq*DKq (elems)
    const int m = m0 + arow;
    const int b = m >> 12, l = m & 4095;
    const size_t abase = ((size_t)b * Hq * Lq + l) * DKq + csw * 8;
    const size_t dbase = (size_t)b * Hq * Lq + l;

    // prologue: prefetch A-regs for h=0
    half8 ph0 = *(const half8*)&op0[abase];
    half8 ph1 = *(const half8*)&op1[abase];
    float pd0 = denp[dbase];
    float pd1 = denp[dbase + (size_t)16 * Lq];

    for (int k0 = 0; k0 < 512; k0 += 64) {
        const int h = k0 >> 6;
        // ---- B staging: async gload_lds (128 rows) ----
#pragma unroll
        for (int i = 0; i < 4; i++) {
            int row = w * 32 + i * 8;
            gload_lds16(&Bw[(size_t)(n0 + row + r8) * 512 + k0 + csw * 8], &sm.s.B[row * 64]);
        }
        // ---- A write: combine from regs prefetched LAST iteration ----
        {
            float rs = __builtin_amdgcn_rcpf(pd0 + pd1);
            float a = pd0 * rs, c = pd1 * rs;
            ushort8 o;
#pragma unroll
            for (int e = 0; e < 8; e++)
                o[e] = f2bf((float)ph0[e] * a + (float)ph1[e] * c);
            *(ushort8*)&sm.s.A[arow * 64 + c8 * 8] = o;
        }
        __syncthreads();
        // ---- prefetch A-regs for h+1 (hidden under frag reads + MFMA) ----
        if (h + 1 < 8) {
            size_t ab = abase + (size_t)(h + 1) * Lq * DKq;
            size_t db = dbase + (size_t)(h + 1) * Lq;
            ph0 = *(const half8*)&op0[ab];
            ph1 = *(const half8*)&op1[ab];
            pd0 = denp[db];
            pd1 = denp[db + (size_t)16 * Lq];
        }
        short8 af0[2], af1[2], bf0[2], bf1[2];
#pragma unroll
        for (int t = 0; t < 2; t++) {
            int rowA = t * 16 + l15;
            af0[t] = *(const short8*)&sm.s.A[rowA * 64 + ((quad ^ sw) * 8)];
            af1[t] = *(const short8*)&sm.s.A[rowA * 64 + (((quad + 4) ^ sw) * 8)];
        }
#pragma unroll
        for (int n = 0; n < 2; n++) {
            int rowB = w * 32 + n * 16 + l15;
            bf0[n] = *(const short8*)&sm.s.B[rowB * 64 + ((quad ^ sw) * 8)];
            bf1[n] = *(const short8*)&sm.s.B[rowB * 64 + (((quad + 4) ^ sw) * 8)];
        }
#pragma unroll
        for (int mi = 0; mi < 2; mi++)
#pragma unroll
            for (int ni = 0; ni < 2; ni++) {
                acc[mi][ni] = mfma16(af0[mi], bf0[ni], acc[mi][ni]);
                acc[mi][ni] = mfma16(af1[mi], bf1[ni], acc[mi][ni]);
            }
        __syncthreads();
    }

    // epilogue: 32x128 fp32 tile via LDS bounce, coalesced float4 stores
#pragma unroll
    for (int mi = 0; mi < 2; mi++)
#pragma unroll
        for (int ni = 0; ni < 2; ni++)
#pragma unroll
            for (int r = 0; r < 4; r++)
                sm.fepi[(mi * 16 + quad * 4 + r) * 132 + w * 32 + ni * 16 + l15] =
                    acc[mi][ni][r];
    __syncthreads();
#pragma unroll
    for (int i = 0; i < 4; i++) {
        int flat = i * 1024 + tid * 4;
        int lrow = flat >> 7, col = flat & 127;
        float4 vv = *(const float4*)&sm.fepi[lrow * 132 + col];
        *(float4*)&out[(size_t)(m0 + lrow) * 512 + n0 + col] = vv;
    }
}

extern "C" void kernel_launch(void* const* d_in, const int* in_sizes, int n_in,
                              void* d_out, int out_size, void* d_ws, size_t ws_size,
                              hipStream_t stream) {
    const float* x     = (const float*)d_in[0];   // [2,4096,512]
    const float* w_qkv = (const float*)d_in[1];   // [1536,512]
    const float* w_o   = (const float*)d_in[2];   // [512,512]
    float* out = (float*)d_out;

    const size_t N_X   = (size_t)Bq * Lq * Dq;        // 4194304
    const size_t N_WQ  = (size_t)3 * Dq * Dq;         // 786432
    const size_t N_WO  = (size_t)Dq * Dq;             // 262144
    const size_t N_QKV = (size_t)Bq * Hq * Lq * DKq;  // 4194304 each

    u16* xb  = (u16*)d_ws;       // castall in; dead after qkv -> op0
    u16* wqb = xb + N_X;         // dead after qkv -> denp
    u16* wob = wqb + N_WQ;
    u16* qb  = wob + N_WO;
    u16* kb  = qb + N_QKV;
    u16* vt  = kb + N_QKV;
    u16* o1r = vt + N_QKV;       // op1 region

    _Float16* op0  = (_Float16*)xb;
    _Float16* op1  = (_Float16*)o1r;
    float*    denp = (float*)wqb;

    castall<<<dim3(5120), 256, 0, stream>>>(x, w_qkv, w_o, xb, wqb, wob);
    qkv_gemm<<<dim3(64, 12), 256, 0, stream>>>(xb, wqb, qb, kb, vt);
    attn_kern<<<dim3(1024), 256, 0, stream>>>(qb, kb, vt, op0, op1, denp);
    out_gemm<<<dim3(256, 4), 256, 0, stream>>>(op0, op1, denp, wob, out);
}